// Round 2
// baseline (1174.005 us; speedup 1.0000x reference)
//
#include <hip/hip_runtime.h>

// 2-layer GCN forward, gather-based (no float atomics).
// ws layout (4-byte elements):
//   int   cnt_out[10000]        -- out-degree counters
//   int   cnt_in [10000]        -- in-degree counters
//   int   esrc   [10000*128]    -- per-dst in-edge source lists (capacity 128)
//   float Y1p    [10*10000*16]  -- GEMM partials, one per 1000-col segment
//   float Y1     [10000*16]     -- reduced + norm_src-scaled layer-1 transform
//   float H2     [10000*8]      -- layer-2 pre-aggregation (7 used, col 7 = 0)

constexpr int NN    = 10000;
constexpr int NE    = 320000;
constexpr int HID   = 16;
constexpr int LAB   = 7;
constexpr int CAP   = 128;    // max in-degree ~ Poisson(32) -> ~70; 128 is safe
constexpr int SEG   = 1000;   // columns per GEMM block (W tile = 64 KB LDS)
constexpr int SEGF4 = SEG / 4;
constexpr int NSEG  = NN / SEG;   // 10
constexpr int GX    = 50;         // row-group blocks per segment
constexpr int WPS   = GX * 8;     // waves per segment = 400

// ---- build counts + capacity-CSR in one pass ----
__global__ void k_count_fill(const int* __restrict__ src, const int* __restrict__ dst,
                             int* __restrict__ cnt_out, int* __restrict__ cnt_in,
                             int* __restrict__ esrc) {
  const int e = blockIdx.x * blockDim.x + threadIdx.x;
  if (e < NE) {
    const int s = src[e], d = dst[e];
    atomicAdd(&cnt_out[s], 1);
    const int p = atomicAdd(&cnt_in[d], 1);
    if (p < CAP) esrc[(d << 7) + p] = s;
  }
}

// ---- Layer-1 GEMM: Y1p[seg][row][k] = sum_{j in seg} F[row,j]*W1[j,k] ----
// Stage-W-once / stream-F: one barrier per block, W1 read once per block.
// grid (50 row-groups, 10 col-segments), 512 threads (8 waves).
// Each wave: 6 chunks of 4 rows (2500 chunks / 400 waves, exact) + 1 tail row
// (400 rows / 400 waves, exact). Butterfly reduce-scatter -> coalesced store.
__global__ __launch_bounds__(512, 4) void k_gemm1(const float* __restrict__ F,
                                                  const float* __restrict__ W1,
                                                  float* __restrict__ Y1p) {
  __shared__ float wT[HID * SEG];   // 64000 B: wT[k*SEG + j], float4-readable
  const int tid  = threadIdx.x;
  const int lane = tid & 63;
  const int wave = tid >> 6;
  const int seg  = blockIdx.y;
  const int j0   = seg * SEG;

  // stage W1[j0..j0+SEG, 0:16] transposed, once
  for (int u = tid; u < SEG * 4; u += 512) {
    const int j = u >> 2, k4 = u & 3;
    const float4 v = *(const float4*)(W1 + (size_t)(j0 + j) * HID + k4 * 4);
    wT[(k4 * 4 + 0) * SEG + j] = v.x;
    wT[(k4 * 4 + 1) * SEG + j] = v.y;
    wT[(k4 * 4 + 2) * SEG + j] = v.z;
    wT[(k4 * 4 + 3) * SEG + j] = v.w;
  }
  __syncthreads();   // the only barrier in this kernel

  const int wg = blockIdx.x * 8 + wave;               // 0..399 within segment
  float* __restrict__ Yo = Y1p + (size_t)seg * NN * HID;
  const float4* __restrict__ F4 = (const float4*)F;
  const int cols0 = j0 >> 2;                          // float4 column base
  constexpr int RS = NN / 4;                          // 2500: row stride in float4

  // ---- 6 rounds of 4-row chunks: rows [0, 9600) ----
  for (int round = 0; round < 6; ++round) {
    const int r0 = (wg + round * WPS) * 4;
    float a[64];                                      // a[m*16+k]
    #pragma unroll
    for (int v = 0; v < 64; ++v) a[v] = 0.0f;
    const size_t b0 = (size_t)r0 * RS + cols0;

    auto do_c = [&](int j4) {
      const float4 f0 = F4[b0 + j4];
      const float4 f1 = F4[b0 + RS + j4];
      const float4 f2 = F4[b0 + 2 * RS + j4];
      const float4 f3 = F4[b0 + 3 * RS + j4];
      #pragma unroll
      for (int k = 0; k < HID; ++k) {
        const float4 w = *(const float4*)(wT + k * SEG + (j4 << 2));
        a[k]      = fmaf(f0.x, w.x, fmaf(f0.y, w.y, fmaf(f0.z, w.z, fmaf(f0.w, w.w, a[k]))));
        a[16 + k] = fmaf(f1.x, w.x, fmaf(f1.y, w.y, fmaf(f1.z, w.z, fmaf(f1.w, w.w, a[16 + k]))));
        a[32 + k] = fmaf(f2.x, w.x, fmaf(f2.y, w.y, fmaf(f2.z, w.z, fmaf(f2.w, w.w, a[32 + k]))));
        a[48 + k] = fmaf(f3.x, w.x, fmaf(f3.y, w.y, fmaf(f3.z, w.z, fmaf(f3.w, w.w, a[48 + k]))));
      }
    };
    #pragma unroll
    for (int c = 0; c < 3; ++c) do_c(c * 64 + lane);  // lanes all active
    { const int j4 = 192 + lane; if (j4 < SEGF4) do_c(j4); }

    // butterfly reduce-scatter: 63 shuffles; lane l ends with total of
    // index l (m = l>>4 row-in-chunk, k = l&15). All shuffles convergent.
    #pragma unroll
    for (int i = 0; i < 32; ++i) {
      const float s0 = (lane & 32) ? a[i] : a[i + 32];
      const float r  = __shfl_xor(s0, 32, 64);
      a[i] = ((lane & 32) ? a[i + 32] : a[i]) + r;
    }
    #pragma unroll
    for (int i = 0; i < 16; ++i) {
      const float s0 = (lane & 16) ? a[i] : a[i + 16];
      const float r  = __shfl_xor(s0, 16, 64);
      a[i] = ((lane & 16) ? a[i + 16] : a[i]) + r;
    }
    #pragma unroll
    for (int i = 0; i < 8; ++i) {
      const float s0 = (lane & 8) ? a[i] : a[i + 8];
      const float r  = __shfl_xor(s0, 8, 64);
      a[i] = ((lane & 8) ? a[i + 8] : a[i]) + r;
    }
    #pragma unroll
    for (int i = 0; i < 4; ++i) {
      const float s0 = (lane & 4) ? a[i] : a[i + 4];
      const float r  = __shfl_xor(s0, 4, 64);
      a[i] = ((lane & 4) ? a[i + 4] : a[i]) + r;
    }
    #pragma unroll
    for (int i = 0; i < 2; ++i) {
      const float s0 = (lane & 2) ? a[i] : a[i + 2];
      const float r  = __shfl_xor(s0, 2, 64);
      a[i] = ((lane & 2) ? a[i + 2] : a[i]) + r;
    }
    {
      const float s0 = (lane & 1) ? a[0] : a[1];
      const float r  = __shfl_xor(s0, 1, 64);
      a[0] = ((lane & 1) ? a[1] : a[0]) + r;
    }
    Yo[(size_t)r0 * HID + lane] = a[0];               // 256 B coalesced store
  }

  // ---- tail: rows [9600, 10000), exactly one per wave ----
  {
    const int row = 9600 + wg;
    float a2[16];
    #pragma unroll
    for (int k = 0; k < 16; ++k) a2[k] = 0.0f;
    const size_t b0 = (size_t)row * RS + cols0;

    auto do_ct = [&](int j4) {
      const float4 f0 = F4[b0 + j4];
      #pragma unroll
      for (int k = 0; k < HID; ++k) {
        const float4 w = *(const float4*)(wT + k * SEG + (j4 << 2));
        a2[k] = fmaf(f0.x, w.x, fmaf(f0.y, w.y, fmaf(f0.z, w.z, fmaf(f0.w, w.w, a2[k]))));
      }
    };
    #pragma unroll
    for (int c = 0; c < 3; ++c) do_ct(c * 64 + lane);
    { const int j4 = 192 + lane; if (j4 < SEGF4) do_ct(j4); }

    #pragma unroll
    for (int k = 0; k < 16; ++k) {
      a2[k] += __shfl_xor(a2[k], 32, 64);
      a2[k] += __shfl_xor(a2[k], 16, 64);
    }
    #pragma unroll
    for (int i = 0; i < 8; ++i) {
      const float s0 = (lane & 8) ? a2[i] : a2[i + 8];
      const float r  = __shfl_xor(s0, 8, 64);
      a2[i] = ((lane & 8) ? a2[i + 8] : a2[i]) + r;
    }
    #pragma unroll
    for (int i = 0; i < 4; ++i) {
      const float s0 = (lane & 4) ? a2[i] : a2[i + 4];
      const float r  = __shfl_xor(s0, 4, 64);
      a2[i] = ((lane & 4) ? a2[i + 4] : a2[i]) + r;
    }
    #pragma unroll
    for (int i = 0; i < 2; ++i) {
      const float s0 = (lane & 2) ? a2[i] : a2[i + 2];
      const float r  = __shfl_xor(s0, 2, 64);
      a2[i] = ((lane & 2) ? a2[i + 2] : a2[i]) + r;
    }
    {
      const float s0 = (lane & 1) ? a2[0] : a2[1];
      const float r  = __shfl_xor(s0, 1, 64);
      a2[0] = ((lane & 1) ? a2[1] : a2[0]) + r;
    }
    if (lane < 16) Yo[(size_t)row * HID + lane] = a2[0];
  }
}

// ---- fold 10 segment partials + apply norm_src ----
__global__ __launch_bounds__(256) void k_scale_reduce(const float* __restrict__ Y1p,
                                                      const int* __restrict__ cnt_out,
                                                      float* __restrict__ Y1) {
  const int t = blockIdx.x * 256 + threadIdx.x;     // float4 index
  if (t >= NN * HID / 4) return;
  const float4* __restrict__ P = (const float4*)Y1p;
  float4 s = P[t];
  #pragma unroll
  for (int g = 1; g < NSEG; ++g) {
    const float4 v = P[(size_t)g * (NN * HID / 4) + t];
    s.x += v.x; s.y += v.y; s.z += v.z; s.w += v.w;
  }
  const int row = t >> 2;
  const float ns = rsqrtf(fmaxf((float)cnt_out[row], 1.0f));
  s.x *= ns; s.y *= ns; s.z *= ns; s.w *= ns;
  ((float4*)Y1)[t] = s;
}

// ---- Fused layer-1 aggregation + relu + bias + layer-2 transform ----
// one wave per node; 64 lanes = 4 edges x 16 features; W2 mix via shuffles.
// NOTE: the h-broadcast shuffle loop MUST run convergently on all 64 lanes —
// placing it under `if (lane < LAB)` lets the compiler sink the computation of
// h into the divergent block, so lanes 7..15 never materialize h and the
// ds_bpermute pulls garbage (caught round 1: absmax 0.134).
__global__ __launch_bounds__(256) void k_gather1(
    const int* __restrict__ cnt_out, const int* __restrict__ cnt_in,
    const int* __restrict__ esrc, const float* __restrict__ Y1,
    const float* __restrict__ b1, const float* __restrict__ W2,
    float* __restrict__ H2) {
  const int tid = threadIdx.x, lane = tid & 63, wave = tid >> 6;
  const int i = blockIdx.x * 4 + wave;               // 2500 blocks x 4 = 10000
  const int nin = cnt_in[i];
  const int n = min(nin, CAP);
  const int* el = esrc + ((size_t)i << 7);
  const int sub = lane >> 4, k = lane & 15;
  float sum = 0.0f;
  for (int e = sub; e < n; e += 4) {
    const int s = el[e];                             // broadcast within 16-lane group
    sum += Y1[s * HID + k];
  }
  sum += __shfl_down(sum, 32, 64);
  sum += __shfl_down(sum, 16, 64);
  // h valid on lanes 0..15 (one per k); computed on ALL lanes (convergent)
  const float ndv = rsqrtf(fmaxf((float)nin, 1.0f));
  const float h = fmaxf(fmaf(sum, ndv, b1[k]), 0.0f);
  // z[c] = norm_src * sum_k h[k] * W2[k][c]; shuffle loop convergent on all
  // 64 lanes (lanes >= LAB read W2 column 0 harmlessly, result discarded)
  const int c = (lane < LAB) ? lane : 0;
  float z = 0.0f;
  #pragma unroll
  for (int kk = 0; kk < HID; ++kk)
    z = fmaf(__shfl(h, kk, 64), W2[kk * LAB + c], z);
  z *= rsqrtf(fmaxf((float)cnt_out[i], 1.0f));
  if (lane < 8) H2[i * 8 + lane] = (lane < LAB) ? z : 0.0f;  // col 7 = 0
}

// ---- Fused layer-2 aggregation + epilogue ----
// one wave per node; 64 lanes = 8 edges x 8 label slots
__global__ __launch_bounds__(256) void k_gather2(
    const int* __restrict__ cnt_in, const int* __restrict__ esrc,
    const float* __restrict__ H2, const float* __restrict__ b2,
    float* __restrict__ out) {
  const int tid = threadIdx.x, lane = tid & 63, wave = tid >> 6;
  const int i = blockIdx.x * 4 + wave;
  const int nin = cnt_in[i];
  const int n = min(nin, CAP);
  const int* el = esrc + ((size_t)i << 7);
  const int sub = lane >> 3, c = lane & 7;
  float sum = 0.0f;
  for (int e = sub; e < n; e += 8) {
    sum += H2[(el[e] << 3) + c];
  }
  sum += __shfl_down(sum, 32, 64);
  sum += __shfl_down(sum, 16, 64);
  sum += __shfl_down(sum, 8, 64);
  if (lane < LAB) {
    const float ndv = rsqrtf(fmaxf((float)nin, 1.0f));
    out[i * LAB + lane] = fmaf(sum, ndv, b2[lane]);
  }
}

extern "C" void kernel_launch(void* const* d_in, const int* in_sizes, int n_in,
                              void* d_out, int out_size, void* d_ws, size_t ws_size,
                              hipStream_t stream) {
  const float* F   = (const float*)d_in[0];
  const int*   src = (const int*)d_in[1];
  const int*   dst = (const int*)d_in[2];
  const float* W1  = (const float*)d_in[3];
  const float* b1  = (const float*)d_in[4];
  const float* W2  = (const float*)d_in[5];
  const float* b2  = (const float*)d_in[6];
  float* out = (float*)d_out;

  int* cnt_out = (int*)d_ws;
  int* cnt_in  = cnt_out + NN;
  int* esrc    = cnt_in + NN;
  float* Y1p   = (float*)(esrc + (size_t)NN * CAP);
  float* Y1    = Y1p + (size_t)NSEG * NN * HID;
  float* H2    = Y1 + (size_t)NN * HID;

  hipMemsetAsync(d_ws, 0, 2 * NN * sizeof(int), stream);
  k_count_fill<<<(NE + 255) / 256, 256, 0, stream>>>(src, dst, cnt_out, cnt_in, esrc);
  k_gemm1<<<dim3(GX, NSEG), 512, 0, stream>>>(F, W1, Y1p);
  k_scale_reduce<<<(NN * HID / 4 + 255) / 256, 256, 0, stream>>>(Y1p, cnt_out, Y1);
  k_gather1<<<NN / 4, 256, 0, stream>>>(cnt_out, cnt_in, esrc, Y1, b1, W2, H2);
  k_gather2<<<NN / 4, 256, 0, stream>>>(cnt_in, esrc, H2, b2, out);
}

// Round 3
// 666.044 us; speedup vs baseline: 1.7627x; 1.7627x over previous
//
#include <hip/hip_runtime.h>

// 2-layer GCN forward, gather-based (no float atomics).
// ws layout (4-byte elements):
//   int   cnt_out[10000]        -- out-degree counters
//   int   cnt_in [10000]        -- in-degree counters
//   int   esrc   [10000*128]    -- per-dst in-edge source lists (capacity 128)
//   float Y1p    [10*10000*16]  -- GEMM partials, one per 1000-col segment
//   float Y1     [10000*16]     -- reduced + norm_src-scaled layer-1 transform
//   float H2     [10000*8]      -- layer-2 pre-aggregation (7 used, col 7 = 0)

constexpr int NN    = 10000;
constexpr int NE    = 320000;
constexpr int HID   = 16;
constexpr int LAB   = 7;
constexpr int CAP   = 128;    // max in-degree ~ Poisson(32) -> ~70; 128 is safe
constexpr int SEG   = 1000;   // columns per GEMM block (W tile = 64 KB LDS)
constexpr int SEGF4 = SEG / 4;
constexpr int NSEG  = NN / SEG;   // 10
constexpr int GX    = 50;         // row-group blocks per segment
constexpr int WPS   = GX * 8;     // waves per segment = 400

// ---- build counts + capacity-CSR in one pass ----
__global__ void k_count_fill(const int* __restrict__ src, const int* __restrict__ dst,
                             int* __restrict__ cnt_out, int* __restrict__ cnt_in,
                             int* __restrict__ esrc) {
  const int e = blockIdx.x * blockDim.x + threadIdx.x;
  if (e < NE) {
    const int s = src[e], d = dst[e];
    atomicAdd(&cnt_out[s], 1);
    const int p = atomicAdd(&cnt_in[d], 1);
    if (p < CAP) esrc[(d << 7) + p] = s;
  }
}

// ---- Layer-1 GEMM: Y1p[seg][row][k] = sum_{j in seg} F[row,j]*W1[j,k] ----
// Stage-W-once / stream-F: one barrier per block, W1 read once per block.
// grid (50 row-groups, 10 col-segments), 512 threads (8 waves).
// REGISTER BUDGET (round-2 post-mortem): 4-row chunks (64 accumulators) made
// the allocator pin 64 VGPRs and spill ~35 regs/round to scratch -> 840 MB of
// spill writes, 733 us. 2-row chunks (32 accumulators, ~55-60 live) fit any
// allocation >= 64 with zero spills. Do not raise rows/chunk without checking
// VGPR_Count and WRITE_SIZE.
// Each wave: 12 chunks of 2 rows (5000 chunks / 400 waves, exact) + 1 tail row
// (400 rows / 400 waves, exact). Butterfly reduce-scatter -> coalesced store.
__global__ __launch_bounds__(512) void k_gemm1(const float* __restrict__ F,
                                               const float* __restrict__ W1,
                                               float* __restrict__ Y1p) {
  __shared__ float wT[HID * SEG];   // 64000 B: wT[k*SEG + j], float4-readable
  const int tid  = threadIdx.x;
  const int lane = tid & 63;
  const int wave = tid >> 6;
  const int seg  = blockIdx.y;
  const int j0   = seg * SEG;

  // stage W1[j0..j0+SEG, 0:16] transposed, once
  for (int u = tid; u < SEG * 4; u += 512) {
    const int j = u >> 2, k4 = u & 3;
    const float4 v = *(const float4*)(W1 + (size_t)(j0 + j) * HID + k4 * 4);
    wT[(k4 * 4 + 0) * SEG + j] = v.x;
    wT[(k4 * 4 + 1) * SEG + j] = v.y;
    wT[(k4 * 4 + 2) * SEG + j] = v.z;
    wT[(k4 * 4 + 3) * SEG + j] = v.w;
  }
  __syncthreads();   // the only barrier in this kernel

  const int wg = blockIdx.x * 8 + wave;               // 0..399 within segment
  float* __restrict__ Yo = Y1p + (size_t)seg * NN * HID;
  const float4* __restrict__ F4 = (const float4*)F;
  const int cols0 = j0 >> 2;                          // float4 column base
  constexpr int RS = NN / 4;                          // 2500: row stride in float4

  // ---- 12 rounds of 2-row chunks: rows [0, 9600) ----
  for (int round = 0; round < 12; ++round) {
    const int r0 = (wg + round * WPS) * 2;
    float a[32];                                      // a[m*16+k], m in {0,1}
    #pragma unroll
    for (int v = 0; v < 32; ++v) a[v] = 0.0f;
    const size_t b0 = (size_t)r0 * RS + cols0;

    auto do_c = [&](int j4) {
      const float4 f0 = F4[b0 + j4];
      const float4 f1 = F4[b0 + RS + j4];
      #pragma unroll
      for (int k = 0; k < HID; ++k) {
        const float4 w = *(const float4*)(wT + k * SEG + (j4 << 2));
        a[k]      = fmaf(f0.x, w.x, fmaf(f0.y, w.y, fmaf(f0.z, w.z, fmaf(f0.w, w.w, a[k]))));
        a[16 + k] = fmaf(f1.x, w.x, fmaf(f1.y, w.y, fmaf(f1.z, w.z, fmaf(f1.w, w.w, a[16 + k]))));
      }
    };
    #pragma unroll
    for (int c = 0; c < 3; ++c) do_c(c * 64 + lane);  // lanes all active
    { const int j4 = 192 + lane; if (j4 < SEGF4) do_c(j4); }

    // reduce-scatter: fold upper half-wave, then 5-level butterfly on 32
    // values; lane l (< 32) ends with the total of index l (m = l>>4,
    // k = l&15). All shuffles convergent.
    #pragma unroll
    for (int i = 0; i < 32; ++i) a[i] += __shfl_xor(a[i], 32, 64);
    #pragma unroll
    for (int i = 0; i < 16; ++i) {
      const float s0 = (lane & 16) ? a[i] : a[i + 16];
      const float r  = __shfl_xor(s0, 16, 64);
      a[i] = ((lane & 16) ? a[i + 16] : a[i]) + r;
    }
    #pragma unroll
    for (int i = 0; i < 8; ++i) {
      const float s0 = (lane & 8) ? a[i] : a[i + 8];
      const float r  = __shfl_xor(s0, 8, 64);
      a[i] = ((lane & 8) ? a[i + 8] : a[i]) + r;
    }
    #pragma unroll
    for (int i = 0; i < 4; ++i) {
      const float s0 = (lane & 4) ? a[i] : a[i + 4];
      const float r  = __shfl_xor(s0, 4, 64);
      a[i] = ((lane & 4) ? a[i + 4] : a[i]) + r;
    }
    #pragma unroll
    for (int i = 0; i < 2; ++i) {
      const float s0 = (lane & 2) ? a[i] : a[i + 2];
      const float r  = __shfl_xor(s0, 2, 64);
      a[i] = ((lane & 2) ? a[i + 2] : a[i]) + r;
    }
    {
      const float s0 = (lane & 1) ? a[0] : a[1];
      const float r  = __shfl_xor(s0, 1, 64);
      a[0] = ((lane & 1) ? a[1] : a[0]) + r;
    }
    if (lane < 32) Yo[(size_t)r0 * HID + lane] = a[0];  // 128 B coalesced store
  }

  // ---- tail: rows [9600, 10000), exactly one per wave ----
  {
    const int row = 9600 + wg;
    float a2[16];
    #pragma unroll
    for (int k = 0; k < 16; ++k) a2[k] = 0.0f;
    const size_t b0 = (size_t)row * RS + cols0;

    auto do_ct = [&](int j4) {
      const float4 f0 = F4[b0 + j4];
      #pragma unroll
      for (int k = 0; k < HID; ++k) {
        const float4 w = *(const float4*)(wT + k * SEG + (j4 << 2));
        a2[k] = fmaf(f0.x, w.x, fmaf(f0.y, w.y, fmaf(f0.z, w.z, fmaf(f0.w, w.w, a2[k]))));
      }
    };
    #pragma unroll
    for (int c = 0; c < 3; ++c) do_ct(c * 64 + lane);
    { const int j4 = 192 + lane; if (j4 < SEGF4) do_ct(j4); }

    #pragma unroll
    for (int k = 0; k < 16; ++k) {
      a2[k] += __shfl_xor(a2[k], 32, 64);
      a2[k] += __shfl_xor(a2[k], 16, 64);
    }
    #pragma unroll
    for (int i = 0; i < 8; ++i) {
      const float s0 = (lane & 8) ? a2[i] : a2[i + 8];
      const float r  = __shfl_xor(s0, 8, 64);
      a2[i] = ((lane & 8) ? a2[i + 8] : a2[i]) + r;
    }
    #pragma unroll
    for (int i = 0; i < 4; ++i) {
      const float s0 = (lane & 4) ? a2[i] : a2[i + 4];
      const float r  = __shfl_xor(s0, 4, 64);
      a2[i] = ((lane & 4) ? a2[i + 4] : a2[i]) + r;
    }
    #pragma unroll
    for (int i = 0; i < 2; ++i) {
      const float s0 = (lane & 2) ? a2[i] : a2[i + 2];
      const float r  = __shfl_xor(s0, 2, 64);
      a2[i] = ((lane & 2) ? a2[i + 2] : a2[i]) + r;
    }
    {
      const float s0 = (lane & 1) ? a2[0] : a2[1];
      const float r  = __shfl_xor(s0, 1, 64);
      a2[0] = ((lane & 1) ? a2[1] : a2[0]) + r;
    }
    if (lane < 16) Yo[(size_t)row * HID + lane] = a2[0];
  }
}

// ---- fold 10 segment partials + apply norm_src ----
__global__ __launch_bounds__(256) void k_scale_reduce(const float* __restrict__ Y1p,
                                                      const int* __restrict__ cnt_out,
                                                      float* __restrict__ Y1) {
  const int t = blockIdx.x * 256 + threadIdx.x;     // float4 index
  if (t >= NN * HID / 4) return;
  const float4* __restrict__ P = (const float4*)Y1p;
  float4 s = P[t];
  #pragma unroll
  for (int g = 1; g < NSEG; ++g) {
    const float4 v = P[(size_t)g * (NN * HID / 4) + t];
    s.x += v.x; s.y += v.y; s.z += v.z; s.w += v.w;
  }
  const int row = t >> 2;
  const float ns = rsqrtf(fmaxf((float)cnt_out[row], 1.0f));
  s.x *= ns; s.y *= ns; s.z *= ns; s.w *= ns;
  ((float4*)Y1)[t] = s;
}

// ---- Fused layer-1 aggregation + relu + bias + layer-2 transform ----
// one wave per node; 64 lanes = 4 edges x 16 features; W2 mix via shuffles.
// NOTE: the h-broadcast shuffle loop MUST run convergently on all 64 lanes —
// placing it under `if (lane < LAB)` lets the compiler sink the computation of
// h into the divergent block, so lanes 7..15 never materialize h and the
// ds_bpermute pulls garbage (caught round 1: absmax 0.134).
__global__ __launch_bounds__(256) void k_gather1(
    const int* __restrict__ cnt_out, const int* __restrict__ cnt_in,
    const int* __restrict__ esrc, const float* __restrict__ Y1,
    const float* __restrict__ b1, const float* __restrict__ W2,
    float* __restrict__ H2) {
  const int tid = threadIdx.x, lane = tid & 63, wave = tid >> 6;
  const int i = blockIdx.x * 4 + wave;               // 2500 blocks x 4 = 10000
  const int nin = cnt_in[i];
  const int n = min(nin, CAP);
  const int* el = esrc + ((size_t)i << 7);
  const int sub = lane >> 4, k = lane & 15;
  float sum = 0.0f;
  for (int e = sub; e < n; e += 4) {
    const int s = el[e];                             // broadcast within 16-lane group
    sum += Y1[s * HID + k];
  }
  sum += __shfl_down(sum, 32, 64);
  sum += __shfl_down(sum, 16, 64);
  // h valid on lanes 0..15 (one per k); computed on ALL lanes (convergent)
  const float ndv = rsqrtf(fmaxf((float)nin, 1.0f));
  const float h = fmaxf(fmaf(sum, ndv, b1[k]), 0.0f);
  // z[c] = norm_src * sum_k h[k] * W2[k][c]; shuffle loop convergent on all
  // 64 lanes (lanes >= LAB read W2 column 0 harmlessly, result discarded)
  const int c = (lane < LAB) ? lane : 0;
  float z = 0.0f;
  #pragma unroll
  for (int kk = 0; kk < HID; ++kk)
    z = fmaf(__shfl(h, kk, 64), W2[kk * LAB + c], z);
  z *= rsqrtf(fmaxf((float)cnt_out[i], 1.0f));
  if (lane < 8) H2[i * 8 + lane] = (lane < LAB) ? z : 0.0f;  // col 7 = 0
}

// ---- Fused layer-2 aggregation + epilogue ----
// one wave per node; 64 lanes = 8 edges x 8 label slots
__global__ __launch_bounds__(256) void k_gather2(
    const int* __restrict__ cnt_in, const int* __restrict__ esrc,
    const float* __restrict__ H2, const float* __restrict__ b2,
    float* __restrict__ out) {
  const int tid = threadIdx.x, lane = tid & 63, wave = tid >> 6;
  const int i = blockIdx.x * 4 + wave;
  const int nin = cnt_in[i];
  const int n = min(nin, CAP);
  const int* el = esrc + ((size_t)i << 7);
  const int sub = lane >> 3, c = lane & 7;
  float sum = 0.0f;
  for (int e = sub; e < n; e += 8) {
    sum += H2[(el[e] << 3) + c];
  }
  sum += __shfl_down(sum, 32, 64);
  sum += __shfl_down(sum, 16, 64);
  sum += __shfl_down(sum, 8, 64);
  if (lane < LAB) {
    const float ndv = rsqrtf(fmaxf((float)nin, 1.0f));
    out[i * LAB + lane] = fmaf(sum, ndv, b2[lane]);
  }
}

extern "C" void kernel_launch(void* const* d_in, const int* in_sizes, int n_in,
                              void* d_out, int out_size, void* d_ws, size_t ws_size,
                              hipStream_t stream) {
  const float* F   = (const float*)d_in[0];
  const int*   src = (const int*)d_in[1];
  const int*   dst = (const int*)d_in[2];
  const float* W1  = (const float*)d_in[3];
  const float* b1  = (const float*)d_in[4];
  const float* W2  = (const float*)d_in[5];
  const float* b2  = (const float*)d_in[6];
  float* out = (float*)d_out;

  int* cnt_out = (int*)d_ws;
  int* cnt_in  = cnt_out + NN;
  int* esrc    = cnt_in + NN;
  float* Y1p   = (float*)(esrc + (size_t)NN * CAP);
  float* Y1    = Y1p + (size_t)NSEG * NN * HID;
  float* H2    = Y1 + (size_t)NN * HID;

  hipMemsetAsync(d_ws, 0, 2 * NN * sizeof(int), stream);
  k_count_fill<<<(NE + 255) / 256, 256, 0, stream>>>(src, dst, cnt_out, cnt_in, esrc);
  k_gemm1<<<dim3(GX, NSEG), 512, 0, stream>>>(F, W1, Y1p);
  k_scale_reduce<<<(NN * HID / 4 + 255) / 256, 256, 0, stream>>>(Y1p, cnt_out, Y1);
  k_gather1<<<NN / 4, 256, 0, stream>>>(cnt_out, cnt_in, esrc, Y1, b1, W2, H2);
  k_gather2<<<NN / 4, 256, 0, stream>>>(cnt_in, esrc, H2, b2, out);
}

// Round 4
// 625.600 us; speedup vs baseline: 1.8766x; 1.0646x over previous
//
#include <hip/hip_runtime.h>

// 2-layer GCN forward, gather-based (no float atomics).
// ws layout (4-byte elements):
//   int   cnt_out[10000]        -- out-degree counters
//   int   cnt_in [10000]        -- in-degree counters
//   int   esrc   [10000*128]    -- per-dst in-edge source lists (capacity 128)
//   float Y1p    [20*10000*16]  -- GEMM partials, one per 500-col segment
//   float Y1     [10000*16]     -- reduced + norm_src-scaled layer-1 transform
//   float H2     [10000*8]      -- layer-2 pre-aggregation (7 used, col 7 = 0)

constexpr int NN    = 10000;
constexpr int NE    = 320000;
constexpr int HID   = 16;
constexpr int LAB   = 7;
constexpr int CAP   = 128;    // max in-degree ~ Poisson(32) -> ~70; 128 is safe
constexpr int SEG   = 500;    // columns per GEMM block (W tile = 32 KB LDS)
constexpr int SEGF4 = SEG / 4;    // 125
constexpr int NSEG  = NN / SEG;   // 20
constexpr int GX    = 50;         // row-group blocks per segment
constexpr int WPS   = GX * 8;     // waves per segment = 400

// ---- build counts + capacity-CSR in one pass ----
__global__ void k_count_fill(const int* __restrict__ src, const int* __restrict__ dst,
                             int* __restrict__ cnt_out, int* __restrict__ cnt_in,
                             int* __restrict__ esrc) {
  const int e = blockIdx.x * blockDim.x + threadIdx.x;
  if (e < NE) {
    const int s = src[e], d = dst[e];
    atomicAdd(&cnt_out[s], 1);
    const int p = atomicAdd(&cnt_in[d], 1);
    if (p < CAP) esrc[(d << 7) + p] = s;
  }
}

// ---- Layer-1 GEMM: Y1p[seg][row][k] = sum_{j in seg} F[row,j]*W1[j,k] ----
// Stage-W-once / stream-F: one barrier per block, W1 read once per block.
// OCCUPANCY (round-3 post-mortem): with SEG=1000 (64 KB LDS) the kernel ran
// 2 blocks/CU = 4 waves/SIMD and measured ~225 us -- 3.5x its ~65 us traffic
// floor, latency-bound. SEG=500 (32 KB LDS) + 1000 blocks gives 4 blocks/CU
// (thread-capped) = 8 waves/SIMD for 2x the in-flight loads.
// REGISTER BUDGET (round-2 post-mortem): 4-row chunks (64 accumulators) made
// the allocator pin 64 VGPRs and spill -> 840 MB scratch writes, 733 us.
// 2-row chunks (32 accumulators) fit any allocation >= 64 with zero spills.
// Do not raise rows/chunk without checking VGPR_Count and WRITE_SIZE.
// Each wave: 12 chunks of 2 rows (4800 of 5000 chunks) + 1 tail row
// (400 rows / 400 waves, exact). Butterfly reduce-scatter -> coalesced store.
__global__ __launch_bounds__(512) void k_gemm1(const float* __restrict__ F,
                                               const float* __restrict__ W1,
                                               float* __restrict__ Y1p) {
  __shared__ float wT[HID * SEG];   // 32000 B: wT[k*SEG + j], float4-readable
  const int tid  = threadIdx.x;
  const int lane = tid & 63;
  const int wave = tid >> 6;
  const int seg  = blockIdx.y;
  const int j0   = seg * SEG;

  // stage W1[j0..j0+SEG, 0:16] transposed, once
  for (int u = tid; u < SEG * 4; u += 512) {
    const int j = u >> 2, k4 = u & 3;
    const float4 v = *(const float4*)(W1 + (size_t)(j0 + j) * HID + k4 * 4);
    wT[(k4 * 4 + 0) * SEG + j] = v.x;
    wT[(k4 * 4 + 1) * SEG + j] = v.y;
    wT[(k4 * 4 + 2) * SEG + j] = v.z;
    wT[(k4 * 4 + 3) * SEG + j] = v.w;
  }
  __syncthreads();   // the only barrier in this kernel

  const int wg = blockIdx.x * 8 + wave;               // 0..399 within segment
  float* __restrict__ Yo = Y1p + (size_t)seg * NN * HID;
  const float4* __restrict__ F4 = (const float4*)F;
  const int cols0 = j0 >> 2;                          // float4 column base
  constexpr int RS = NN / 4;                          // 2500: row stride in float4

  // ---- 12 rounds of 2-row chunks: rows [0, 9600) ----
  for (int round = 0; round < 12; ++round) {
    const int r0 = (wg + round * WPS) * 2;
    float a[32];                                      // a[m*16+k], m in {0,1}
    #pragma unroll
    for (int v = 0; v < 32; ++v) a[v] = 0.0f;
    const size_t b0 = (size_t)r0 * RS + cols0;

    auto do_c = [&](int j4) {
      const float4 f0 = F4[b0 + j4];
      const float4 f1 = F4[b0 + RS + j4];
      #pragma unroll
      for (int k = 0; k < HID; ++k) {
        const float4 w = *(const float4*)(wT + k * SEG + (j4 << 2));
        a[k]      = fmaf(f0.x, w.x, fmaf(f0.y, w.y, fmaf(f0.z, w.z, fmaf(f0.w, w.w, a[k]))));
        a[16 + k] = fmaf(f1.x, w.x, fmaf(f1.y, w.y, fmaf(f1.z, w.z, fmaf(f1.w, w.w, a[16 + k]))));
      }
    };
    do_c(lane);                                       // j4 in [0,64)
    { const int j4 = 64 + lane; if (j4 < SEGF4) do_c(j4); }  // [64,125)

    // reduce-scatter: fold upper half-wave, then 5-level butterfly on 32
    // values; lane l (< 32) ends with the total of index l (m = l>>4,
    // k = l&15). All shuffles convergent.
    #pragma unroll
    for (int i = 0; i < 32; ++i) a[i] += __shfl_xor(a[i], 32, 64);
    #pragma unroll
    for (int i = 0; i < 16; ++i) {
      const float s0 = (lane & 16) ? a[i] : a[i + 16];
      const float r  = __shfl_xor(s0, 16, 64);
      a[i] = ((lane & 16) ? a[i + 16] : a[i]) + r;
    }
    #pragma unroll
    for (int i = 0; i < 8; ++i) {
      const float s0 = (lane & 8) ? a[i] : a[i + 8];
      const float r  = __shfl_xor(s0, 8, 64);
      a[i] = ((lane & 8) ? a[i + 8] : a[i]) + r;
    }
    #pragma unroll
    for (int i = 0; i < 4; ++i) {
      const float s0 = (lane & 4) ? a[i] : a[i + 4];
      const float r  = __shfl_xor(s0, 4, 64);
      a[i] = ((lane & 4) ? a[i + 4] : a[i]) + r;
    }
    #pragma unroll
    for (int i = 0; i < 2; ++i) {
      const float s0 = (lane & 2) ? a[i] : a[i + 2];
      const float r  = __shfl_xor(s0, 2, 64);
      a[i] = ((lane & 2) ? a[i + 2] : a[i]) + r;
    }
    {
      const float s0 = (lane & 1) ? a[0] : a[1];
      const float r  = __shfl_xor(s0, 1, 64);
      a[0] = ((lane & 1) ? a[1] : a[0]) + r;
    }
    if (lane < 32) Yo[(size_t)r0 * HID + lane] = a[0];  // 128 B coalesced store
  }

  // ---- tail: rows [9600, 10000), exactly one per wave ----
  {
    const int row = 9600 + wg;
    float a2[16];
    #pragma unroll
    for (int k = 0; k < 16; ++k) a2[k] = 0.0f;
    const size_t b0 = (size_t)row * RS + cols0;

    auto do_ct = [&](int j4) {
      const float4 f0 = F4[b0 + j4];
      #pragma unroll
      for (int k = 0; k < HID; ++k) {
        const float4 w = *(const float4*)(wT + k * SEG + (j4 << 2));
        a2[k] = fmaf(f0.x, w.x, fmaf(f0.y, w.y, fmaf(f0.z, w.z, fmaf(f0.w, w.w, a2[k]))));
      }
    };
    do_ct(lane);
    { const int j4 = 64 + lane; if (j4 < SEGF4) do_ct(j4); }

    #pragma unroll
    for (int k = 0; k < 16; ++k) {
      a2[k] += __shfl_xor(a2[k], 32, 64);
      a2[k] += __shfl_xor(a2[k], 16, 64);
    }
    #pragma unroll
    for (int i = 0; i < 8; ++i) {
      const float s0 = (lane & 8) ? a2[i] : a2[i + 8];
      const float r  = __shfl_xor(s0, 8, 64);
      a2[i] = ((lane & 8) ? a2[i + 8] : a2[i]) + r;
    }
    #pragma unroll
    for (int i = 0; i < 4; ++i) {
      const float s0 = (lane & 4) ? a2[i] : a2[i + 4];
      const float r  = __shfl_xor(s0, 4, 64);
      a2[i] = ((lane & 4) ? a2[i + 4] : a2[i]) + r;
    }
    #pragma unroll
    for (int i = 0; i < 2; ++i) {
      const float s0 = (lane & 2) ? a2[i] : a2[i + 2];
      const float r  = __shfl_xor(s0, 2, 64);
      a2[i] = ((lane & 2) ? a2[i + 2] : a2[i]) + r;
    }
    {
      const float s0 = (lane & 1) ? a2[0] : a2[1];
      const float r  = __shfl_xor(s0, 1, 64);
      a2[0] = ((lane & 1) ? a2[1] : a2[0]) + r;
    }
    if (lane < 16) Yo[(size_t)row * HID + lane] = a2[0];
  }
}

// ---- fold 20 segment partials + apply norm_src ----
__global__ __launch_bounds__(256) void k_scale_reduce(const float* __restrict__ Y1p,
                                                      const int* __restrict__ cnt_out,
                                                      float* __restrict__ Y1) {
  const int t = blockIdx.x * 256 + threadIdx.x;     // float4 index
  if (t >= NN * HID / 4) return;
  const float4* __restrict__ P = (const float4*)Y1p;
  float4 s = P[t];
  #pragma unroll
  for (int g = 1; g < NSEG; ++g) {
    const float4 v = P[(size_t)g * (NN * HID / 4) + t];
    s.x += v.x; s.y += v.y; s.z += v.z; s.w += v.w;
  }
  const int row = t >> 2;
  const float ns = rsqrtf(fmaxf((float)cnt_out[row], 1.0f));
  s.x *= ns; s.y *= ns; s.z *= ns; s.w *= ns;
  ((float4*)Y1)[t] = s;
}

// ---- Fused layer-1 aggregation + relu + bias + layer-2 transform ----
// one wave per node; 64 lanes = 4 edges x 16 features; W2 mix via shuffles.
// NOTE: the h-broadcast shuffle loop MUST run convergently on all 64 lanes —
// placing it under `if (lane < LAB)` lets the compiler sink the computation of
// h into the divergent block, so lanes 7..15 never materialize h and the
// ds_bpermute pulls garbage (caught round 1: absmax 0.134).
__global__ __launch_bounds__(256) void k_gather1(
    const int* __restrict__ cnt_out, const int* __restrict__ cnt_in,
    const int* __restrict__ esrc, const float* __restrict__ Y1,
    const float* __restrict__ b1, const float* __restrict__ W2,
    float* __restrict__ H2) {
  const int tid = threadIdx.x, lane = tid & 63, wave = tid >> 6;
  const int i = blockIdx.x * 4 + wave;               // 2500 blocks x 4 = 10000
  const int nin = cnt_in[i];
  const int n = min(nin, CAP);
  const int* el = esrc + ((size_t)i << 7);
  const int sub = lane >> 4, k = lane & 15;
  float sum = 0.0f;
  for (int e = sub; e < n; e += 4) {
    const int s = el[e];                             // broadcast within 16-lane group
    sum += Y1[s * HID + k];
  }
  sum += __shfl_down(sum, 32, 64);
  sum += __shfl_down(sum, 16, 64);
  // h valid on lanes 0..15 (one per k); computed on ALL lanes (convergent)
  const float ndv = rsqrtf(fmaxf((float)nin, 1.0f));
  const float h = fmaxf(fmaf(sum, ndv, b1[k]), 0.0f);
  // z[c] = norm_src * sum_k h[k] * W2[k][c]; shuffle loop convergent on all
  // 64 lanes (lanes >= LAB read W2 column 0 harmlessly, result discarded)
  const int c = (lane < LAB) ? lane : 0;
  float z = 0.0f;
  #pragma unroll
  for (int kk = 0; kk < HID; ++kk)
    z = fmaf(__shfl(h, kk, 64), W2[kk * LAB + c], z);
  z *= rsqrtf(fmaxf((float)cnt_out[i], 1.0f));
  if (lane < 8) H2[i * 8 + lane] = (lane < LAB) ? z : 0.0f;  // col 7 = 0
}

// ---- Fused layer-2 aggregation + epilogue ----
// one wave per node; 64 lanes = 8 edges x 8 label slots
__global__ __launch_bounds__(256) void k_gather2(
    const int* __restrict__ cnt_in, const int* __restrict__ esrc,
    const float* __restrict__ H2, const float* __restrict__ b2,
    float* __restrict__ out) {
  const int tid = threadIdx.x, lane = tid & 63, wave = tid >> 6;
  const int i = blockIdx.x * 4 + wave;
  const int nin = cnt_in[i];
  const int n = min(nin, CAP);
  const int* el = esrc + ((size_t)i << 7);
  const int sub = lane >> 3, c = lane & 7;
  float sum = 0.0f;
  for (int e = sub; e < n; e += 8) {
    sum += H2[(el[e] << 3) + c];
  }
  sum += __shfl_down(sum, 32, 64);
  sum += __shfl_down(sum, 16, 64);
  sum += __shfl_down(sum, 8, 64);
  if (lane < LAB) {
    const float ndv = rsqrtf(fmaxf((float)nin, 1.0f));
    out[i * LAB + lane] = fmaf(sum, ndv, b2[lane]);
  }
}

extern "C" void kernel_launch(void* const* d_in, const int* in_sizes, int n_in,
                              void* d_out, int out_size, void* d_ws, size_t ws_size,
                              hipStream_t stream) {
  const float* F   = (const float*)d_in[0];
  const int*   src = (const int*)d_in[1];
  const int*   dst = (const int*)d_in[2];
  const float* W1  = (const float*)d_in[3];
  const float* b1  = (const float*)d_in[4];
  const float* W2  = (const float*)d_in[5];
  const float* b2  = (const float*)d_in[6];
  float* out = (float*)d_out;

  int* cnt_out = (int*)d_ws;
  int* cnt_in  = cnt_out + NN;
  int* esrc    = cnt_in + NN;
  float* Y1p   = (float*)(esrc + (size_t)NN * CAP);
  float* Y1    = Y1p + (size_t)NSEG * NN * HID;
  float* H2    = Y1 + (size_t)NN * HID;

  hipMemsetAsync(d_ws, 0, 2 * NN * sizeof(int), stream);
  k_count_fill<<<(NE + 255) / 256, 256, 0, stream>>>(src, dst, cnt_out, cnt_in, esrc);
  k_gemm1<<<dim3(GX, NSEG), 512, 0, stream>>>(F, W1, Y1p);
  k_scale_reduce<<<(NN * HID / 4 + 255) / 256, 256, 0, stream>>>(Y1p, cnt_out, Y1);
  k_gather1<<<NN / 4, 256, 0, stream>>>(cnt_out, cnt_in, esrc, Y1, b1, W2, H2);
  k_gather2<<<NN / 4, 256, 0, stream>>>(cnt_in, esrc, H2, b2, out);
}